// Round 1
// baseline (671.879 us; speedup 1.0000x reference)
//
#include <hip/hip_runtime.h>
#include <stdint.h>

typedef __attribute__((ext_vector_type(4))) float f32x4;
typedef __attribute__((ext_vector_type(8))) __bf16 bf16x8;
typedef __attribute__((ext_vector_type(4))) unsigned int u32x4;
typedef __attribute__((ext_vector_type(4))) unsigned short u16x4;

#define TOK 49
#define NHEAD 16
#define HDIM 32
#define CDIM 512
#define NB 2048
#define MTOT (NB * TOK) /* 100352 */
#define ATT_SCALE 0.17677669529663687f

__device__ __forceinline__ unsigned short f2bf(float f) {
  uint32_t u = __builtin_bit_cast(uint32_t, f);
  u += 0x7FFFu + ((u >> 16) & 1u);
  return (unsigned short)(u >> 16);
}

__device__ __forceinline__ void gl_lds16(const void* g, const void* lds) {
  __builtin_amdgcn_global_load_lds(
      (__attribute__((address_space(1))) void*)(uintptr_t)g,
      (__attribute__((address_space(3))) void*)(uint32_t)(uintptr_t)lds,
      16, 0, 0);
}

__device__ __forceinline__ f32x4 mfma16(bf16x8 a, bf16x8 b, f32x4 c) {
  return __builtin_amdgcn_mfma_f32_16x16x32_bf16(a, b, c, 0, 0, 0);
}

// ---- K0a: W_eff = W_qkv + B_up @ A_down, to bf16 [1536][512] ----
__global__ __launch_bounds__(256) void k_prep_weff(
    const float* __restrict__ Wqkv, const float* __restrict__ Bup,
    const float* __restrict__ Adown, unsigned short* __restrict__ weff) {
  int idx = blockIdx.x * 256 + threadIdx.x;
  if (idx >= 3 * CDIM * CDIM) return;
  int o = idx >> 9, i = idx & 511;
  float v = Wqkv[idx];
#pragma unroll
  for (int r = 0; r < 4; r++) v += Bup[o * 4 + r] * Adown[r * 512 + i];
  weff[idx] = f2bf(v);
}

// ---- K0b: fp32 -> bf16 vectorized convert ----
__global__ __launch_bounds__(256) void k_conv4(
    const float* __restrict__ src, unsigned short* __restrict__ dst, int n4) {
  for (int i = blockIdx.x * blockDim.x + threadIdx.x; i < n4;
       i += gridDim.x * blockDim.x) {
    f32x4 v = *(const f32x4*)(src + (size_t)i * 4);
    u16x4 o;
    o[0] = f2bf(v[0]); o[1] = f2bf(v[1]); o[2] = f2bf(v[2]); o[3] = f2bf(v[3]);
    *(u16x4*)(dst + (size_t)i * 4) = o;
  }
}

// ---- K1/K3: 128x128 tile bf16 GEMM, C = A @ Bw^T + bias ----
// A [M][512] bf16 row-major, Bw [N][512] bf16 row-major (i.e. B^T form).
template <int NTILES, bool SPLIT_QKV>
__global__ __launch_bounds__(256) void k_gemm(
    const unsigned short* __restrict__ A, const unsigned short* __restrict__ Bw,
    const float* __restrict__ bias,
    unsigned short* __restrict__ qo, unsigned short* __restrict__ ko,
    unsigned short* __restrict__ vo, float* __restrict__ fo) {
  __shared__ __attribute__((aligned(16))) unsigned short lA[128 * 32];
  __shared__ __attribute__((aligned(16))) unsigned short lB[128 * 32];
  const int t = threadIdx.x;
  const int l = t & 63;
  const int w = t >> 6;
  const int l15 = l & 15, lq = l >> 4;
  const int wr = w >> 1, wc = w & 1;
  const int bid = blockIdx.x;
  const int mt = bid / NTILES, nt = bid % NTILES;
  const size_t m0 = (size_t)mt * 128;
  const int n0 = nt * 128;

  const unsigned short* aS0 = A + (m0 + (t >> 2)) * CDIM + (t & 3) * 8;
  const unsigned short* aS1 = aS0 + 64 * CDIM;
  const unsigned short* bS0 = Bw + (size_t)(n0 + (t >> 2)) * CDIM + (t & 3) * 8;
  const unsigned short* bS1 = bS0 + 64 * CDIM;
  unsigned short* aD0 = lA + t * 8;
  unsigned short* aD1 = lA + 2048 + t * 8;
  unsigned short* bD0 = lB + t * 8;
  unsigned short* bD1 = lB + 2048 + t * 8;

  f32x4 acc[4][4] = {};
  for (int kt = 0; kt < CDIM / 32; ++kt) {
    const int kofs = kt * 32;
    gl_lds16(aS0 + kofs, aD0);
    gl_lds16(aS1 + kofs, aD1);
    gl_lds16(bS0 + kofs, bD0);
    gl_lds16(bS1 + kofs, bD1);
    __syncthreads();
    bf16x8 af[4], bfr[4];
#pragma unroll
    for (int i = 0; i < 4; i++)
      af[i] = __builtin_bit_cast(
          bf16x8, *(const u32x4*)&lA[(wr * 64 + i * 16 + l15) * 32 + lq * 8]);
#pragma unroll
    for (int i = 0; i < 4; i++)
      bfr[i] = __builtin_bit_cast(
          bf16x8, *(const u32x4*)&lB[(wc * 64 + i * 16 + l15) * 32 + lq * 8]);
#pragma unroll
    for (int i = 0; i < 4; i++) {
#pragma unroll
      for (int j = 0; j < 4; j++) acc[i][j] = mfma16(af[i], bfr[j], acc[i][j]);
    }
    __syncthreads();
  }

#pragma unroll
  for (int j = 0; j < 4; j++) {
    const int colb = n0 + wc * 64 + j * 16 + l15;
    const float bv = bias[colb];
    if constexpr (SPLIT_QKV) {
      const int which = colb >> 9;
      const int hh = (colb >> 5) & 15;
      const int d = colb & 31;
      unsigned short* dst = which == 0 ? qo : (which == 1 ? ko : vo);
#pragma unroll
      for (int i = 0; i < 4; i++) {
#pragma unroll
        for (int r = 0; r < 4; r++) {
          uint32_t m = (uint32_t)(m0 + wr * 64 + i * 16 + lq * 4 + r);
          uint32_t bw_ = m / 49u;
          uint32_t nn = m - bw_ * 49u;
          dst[((size_t)(bw_ * 16u + hh) * 49u + nn) * 32u + d] =
              f2bf(acc[i][j][r] + bv);
        }
      }
    } else {
#pragma unroll
      for (int i = 0; i < 4; i++) {
#pragma unroll
        for (int r = 0; r < 4; r++) {
          size_t m = m0 + wr * 64 + i * 16 + lq * 4 + r;
          fo[m * CDIM + colb] = acc[i][j][r] + bv;
        }
      }
    }
  }
}

// ---- K2: window attention, one wave per (b,h) ----
__global__ __launch_bounds__(256) void k_attn(
    const unsigned short* __restrict__ qb, const unsigned short* __restrict__ kb,
    const unsigned short* __restrict__ vb, const float* __restrict__ mask,
    unsigned short* __restrict__ ao) {
  __shared__ __attribute__((aligned(16))) unsigned short sP[4][64 * 72];
  __shared__ __attribute__((aligned(16))) unsigned short sV[4][32 * 72];
  const int t = threadIdx.x;
  const int l = t & 63, w = t >> 6;
  const int l15 = l & 15, lq = l >> 4;
  const int pair = blockIdx.x * 4 + w;
  const int b = pair >> 4, h = pair & 15;
  const size_t base = (size_t)pair * (TOK * HDIM);
  unsigned short* P = sP[w];
  unsigned short* Vt = sV[w];

  // Q, K fragments straight from global (A/B layout: row=l&15, k=(l>>4)*8+j)
  bf16x8 qf[4], kf[4];
#pragma unroll
  for (int i = 0; i < 4; i++)
    qf[i] = __builtin_bit_cast(
        bf16x8, *(const u32x4*)(qb + base + (size_t)(i * 16 + l15) * 32 + lq * 8));
#pragma unroll
  for (int i = 0; i < 4; i++)
    kf[i] = __builtin_bit_cast(
        bf16x8, *(const u32x4*)(kb + base + (size_t)(i * 16 + l15) * 32 + lq * 8));
  // V rows: lane l holds token l
  u32x4 vr[4];
#pragma unroll
  for (int j = 0; j < 4; j++)
    vr[j] = *(const u32x4*)(vb + base + (size_t)l * 32 + j * 8);

  // S = Q K^T  (64x64 padded; valid 49x49)
  f32x4 s[4][4];
#pragma unroll
  for (int i = 0; i < 4; i++) {
#pragma unroll
    for (int j = 0; j < 4; j++) s[i][j] = mfma16(qf[i], kf[j], (f32x4)0.0f);
  }

  // V^T -> LDS [d=32][token=64], zero-padded tokens >= 49
  const bool vok = (l < TOK);
#pragma unroll
  for (int j = 0; j < 4; j++) {
#pragma unroll
    for (int c = 0; c < 4; c++) {
      uint32_t u = vr[j][c];
      int d = j * 8 + c * 2;
      Vt[(d + 0) * 72 + l] = vok ? (unsigned short)(u & 0xFFFFu) : (unsigned short)0;
      Vt[(d + 1) * 72 + l] = vok ? (unsigned short)(u >> 16) : (unsigned short)0;
    }
  }

  // scale + window mask
  const float* mrow = mask + (size_t)(b & 63) * (TOK * TOK);
#pragma unroll
  for (int i = 0; i < 4; i++) {
#pragma unroll
    for (int r = 0; r < 4; r++) {
      int row = i * 16 + lq * 4 + r;
#pragma unroll
      for (int j = 0; j < 4; j++) {
        int col = j * 16 + l15;
        float xv = s[i][j][r] * ATT_SCALE;
        if (col < TOK) {
          if (row < TOK) xv += mrow[row * TOK + col];
        } else {
          xv = -1e30f;
        }
        s[i][j][r] = xv;
      }
    }
  }

  // row softmax (rows live on 16-lane groups); unnormalized P -> LDS bf16
  float rinv[4][4];
#pragma unroll
  for (int i = 0; i < 4; i++) {
#pragma unroll
    for (int r = 0; r < 4; r++) {
      float m = fmaxf(fmaxf(s[i][0][r], s[i][1][r]), fmaxf(s[i][2][r], s[i][3][r]));
      m = fmaxf(m, __shfl_xor(m, 1));
      m = fmaxf(m, __shfl_xor(m, 2));
      m = fmaxf(m, __shfl_xor(m, 4));
      m = fmaxf(m, __shfl_xor(m, 8));
      float sum = 0.f;
      int row = i * 16 + lq * 4 + r;
#pragma unroll
      for (int j = 0; j < 4; j++) {
        float p = __expf(s[i][j][r] - m);
        sum += p;
        P[row * 72 + j * 16 + l15] = f2bf(p);
      }
      sum += __shfl_xor(sum, 1);
      sum += __shfl_xor(sum, 2);
      sum += __shfl_xor(sum, 4);
      sum += __shfl_xor(sum, 8);
      rinv[i][r] = 1.0f / sum;
    }
  }

  asm volatile("s_waitcnt lgkmcnt(0)" ::: "memory");

  // O = P @ V  (K = 64 padded tokens, N = 32 dims)
  f32x4 o[4][2] = {};
#pragma unroll
  for (int ks = 0; ks < 2; ks++) {
    bf16x8 pa[4], vf[2];
#pragma unroll
    for (int i = 0; i < 4; i++)
      pa[i] = __builtin_bit_cast(
          bf16x8, *(const u32x4*)&P[(i * 16 + l15) * 72 + lq * 8 + ks * 32]);
#pragma unroll
    for (int j = 0; j < 2; j++)
      vf[j] = __builtin_bit_cast(
          bf16x8, *(const u32x4*)&Vt[(j * 16 + l15) * 72 + lq * 8 + ks * 32]);
#pragma unroll
    for (int i = 0; i < 4; i++) {
#pragma unroll
      for (int j = 0; j < 2; j++) o[i][j] = mfma16(pa[i], vf[j], o[i][j]);
    }
  }

  // O write: ao[b*49+row][h*32+d] bf16, scaled by 1/rowsum
#pragma unroll
  for (int i = 0; i < 4; i++) {
#pragma unroll
    for (int r = 0; r < 4; r++) {
      int row = i * 16 + lq * 4 + r;
      if (row < TOK) {
        float inv = rinv[i][r];
        size_t obase = ((size_t)b * TOK + row) * CDIM + h * HDIM;
#pragma unroll
        for (int j = 0; j < 2; j++)
          ao[obase + j * 16 + l15] = f2bf(o[i][j][r] * inv);
      }
    }
  }
}

extern "C" void kernel_launch(void* const* d_in, const int* in_sizes, int n_in,
                              void* d_out, int out_size, void* d_ws,
                              size_t ws_size, hipStream_t stream) {
  const float* x = (const float*)d_in[0];
  const float* mask = (const float*)d_in[1];
  const float* Wqkv = (const float*)d_in[2];
  const float* bqkv = (const float*)d_in[3];
  const float* Adown = (const float*)d_in[4];
  const float* Bup = (const float*)d_in[5];
  const float* Wproj = (const float*)d_in[6];
  const float* bproj = (const float*)d_in[7];
  float* out = (float*)d_out;
  char* ws = (char*)d_ws;

  size_t off = 0;
  auto alloc = [&](size_t bytes) {
    size_t o = off;
    off += (bytes + 255) & ~(size_t)255;
    return o;
  };
  const size_t qkv_elems = (size_t)NB * NHEAD * TOK * HDIM;  // 51,380,224
  unsigned short* weff = (unsigned short*)(ws + alloc((size_t)3 * CDIM * CDIM * 2));
  unsigned short* wpb = (unsigned short*)(ws + alloc((size_t)CDIM * CDIM * 2));
  unsigned short* qb = (unsigned short*)(ws + alloc(qkv_elems * 2 + 4096));
  unsigned short* kb = (unsigned short*)(ws + alloc(qkv_elems * 2 + 4096));
  unsigned short* vb = (unsigned short*)(ws + alloc(qkv_elems * 2 + 4096));
  unsigned short* xb = (unsigned short*)(ws + alloc((size_t)MTOT * CDIM * 2));
  unsigned short* ao = xb;  // xb dead after QKV GEMM; reuse for attention out

  k_prep_weff<<<(3 * CDIM * CDIM + 255) / 256, 256, 0, stream>>>(Wqkv, Bup,
                                                                 Adown, weff);
  k_conv4<<<256, 256, 0, stream>>>(Wproj, wpb, CDIM * CDIM / 4);
  k_conv4<<<2048, 256, 0, stream>>>(x, xb, MTOT * CDIM / 4);
  k_gemm<12, true><<<(MTOT / 128) * 12, 256, 0, stream>>>(
      xb, weff, bqkv, qb, kb, vb, nullptr);
  k_attn<<<NB * NHEAD / 4, 256, 0, stream>>>(qb, kb, vb, mask, ao);
  k_gemm<4, false><<<(MTOT / 128) * 4, 256, 0, stream>>>(
      ao, wpb, bproj, nullptr, nullptr, nullptr, out);
}

// Round 2
// 627.548 us; speedup vs baseline: 1.0706x; 1.0706x over previous
//
#include <hip/hip_runtime.h>
#include <stdint.h>

typedef __attribute__((ext_vector_type(4))) float f32x4;
typedef __attribute__((ext_vector_type(8))) __bf16 bf16x8;
typedef __attribute__((ext_vector_type(4))) unsigned int u32x4;
typedef __attribute__((ext_vector_type(4))) unsigned short u16x4;

#define TOK 49
#define NHEAD 16
#define HDIM 32
#define CDIM 512
#define NB 2048
#define MTOT (NB * TOK) /* 100352 */
#define ATT_SCALE 0.17677669529663687f

__device__ __forceinline__ unsigned short f2bf(float f) {
  uint32_t u = __builtin_bit_cast(uint32_t, f);
  u += 0x7FFFu + ((u >> 16) & 1u);
  return (unsigned short)(u >> 16);
}

__device__ __forceinline__ void gl_lds16(const void* g, const void* lds) {
  __builtin_amdgcn_global_load_lds(
      (__attribute__((address_space(1))) void*)(uintptr_t)g,
      (__attribute__((address_space(3))) void*)(uint32_t)(uintptr_t)lds,
      16, 0, 0);
}

__device__ __forceinline__ f32x4 mfma16(bf16x8 a, bf16x8 b, f32x4 c) {
  return __builtin_amdgcn_mfma_f32_16x16x32_bf16(a, b, c, 0, 0, 0);
}

// ---- K0a: W_eff = W_qkv + B_up @ A_down, to bf16 [1536][512] ----
__global__ __launch_bounds__(256) void k_prep_weff(
    const float* __restrict__ Wqkv, const float* __restrict__ Bup,
    const float* __restrict__ Adown, unsigned short* __restrict__ weff) {
  int idx = blockIdx.x * 256 + threadIdx.x;
  if (idx >= 3 * CDIM * CDIM) return;
  int o = idx >> 9, i = idx & 511;
  float v = Wqkv[idx];
#pragma unroll
  for (int r = 0; r < 4; r++) v += Bup[o * 4 + r] * Adown[r * 512 + i];
  weff[idx] = f2bf(v);
}

// ---- K0b: fp32 -> bf16 vectorized convert ----
__global__ __launch_bounds__(256) void k_conv4(
    const float* __restrict__ src, unsigned short* __restrict__ dst, int n4) {
  for (int i = blockIdx.x * blockDim.x + threadIdx.x; i < n4;
       i += gridDim.x * blockDim.x) {
    f32x4 v = *(const f32x4*)(src + (size_t)i * 4);
    u16x4 o;
    o[0] = f2bf(v[0]); o[1] = f2bf(v[1]); o[2] = f2bf(v[2]); o[3] = f2bf(v[3]);
    *(u16x4*)(dst + (size_t)i * 4) = o;
  }
}

// ---- 256x256 tile, BK=64, 8-wave, counted-vmcnt phase-pipelined GEMM ----
// C = A @ Bw^T + bias. A [M][512] bf16, Bw [N][512] bf16 (B^T form).
// LDS tiles hold 16B slots XOR-swizzled: LDS[row][slot] = G[row][slot^(row&7)]
// (achieved by pre-swizzling the *global* source of global_load_lds; LDS dest
// stays linear per the wave-uniform-base+lane*16 rule).
template <int NT, bool SPLIT>
__global__ __launch_bounds__(512, 1) void k_gemm256(
    const unsigned short* __restrict__ A, const unsigned short* __restrict__ Bw,
    const float* __restrict__ bias,
    unsigned short* __restrict__ qo, unsigned short* __restrict__ ko,
    unsigned short* __restrict__ vo, float* __restrict__ fo) {
  __shared__ __attribute__((aligned(16))) unsigned short lA[2][256 * 64];
  __shared__ __attribute__((aligned(16))) unsigned short lB[2][256 * 64];
  const int t = threadIdx.x;
  const int l = t & 63;
  const int l15 = l & 15, lq = l >> 4;
  const int w = t >> 6;
  const int wr = w >> 2, wc = w & 3;  // 2 x 4 wave grid, wave owns 128x64
  // XCD-aware bijective swizzle (grid % 8 == 0 for both instantiations)
  const int bid = blockIdx.x;
  const int lb = (bid & 7) * ((int)gridDim.x >> 3) + (bid >> 3);
  const int mt = lb / NT, nt = lb % NT;
  const size_t m0 = (size_t)mt * 256;
  const int n0 = nt * 256;

  auto stage = [&](int kt, int bb) {
#pragma unroll
    for (int q = 0; q < 4; ++q) {
      const int li = q * 512 + t;  // linear 16B-chunk index in 256x64 tile
      const int row = li >> 3, sl = li & 7;
      gl_lds16(A + (m0 + row) * CDIM + kt * 64 + ((sl ^ (row & 7)) << 3),
               &lA[bb][li * 8]);
    }
#pragma unroll
    for (int q = 0; q < 4; ++q) {
      const int li = q * 512 + t;
      const int row = li >> 3, sl = li & 7;
      gl_lds16(Bw + (size_t)(n0 + row) * CDIM + kt * 64 + ((sl ^ (row & 7)) << 3),
               &lB[bb][li * 8]);
    }
  };

  f32x4 acc[8][4] = {};
  stage(0, 0);
  for (int kt = 0; kt < 8; ++kt) {
    const int cur = kt & 1;
    if (kt < 7) {
      stage(kt + 1, cur ^ 1);
      // tile kt's 8 loads done; tile kt+1's 8 stay in flight (counted, not 0)
      asm volatile("s_waitcnt vmcnt(8)" ::: "memory");
    } else {
      asm volatile("s_waitcnt vmcnt(0)" ::: "memory");
    }
    __builtin_amdgcn_s_barrier();
    asm volatile("" ::: "memory");  // keep ds_reads below the barrier
    const unsigned short* bufA = &lA[cur][0];
    const unsigned short* bufB = &lB[cur][0];
#pragma unroll
    for (int p = 0; p < 4; ++p) {
      const int qi = p >> 1, qj = p & 1;  // output quadrant 64(row) x 32(col)
      bf16x8 af[4][2], bfr[2][2];
#pragma unroll
      for (int i = 0; i < 4; ++i) {
        const int r = wr * 128 + qi * 64 + i * 16 + l15;
#pragma unroll
        for (int h = 0; h < 2; ++h)
          af[i][h] = __builtin_bit_cast(
              bf16x8,
              *(const u32x4*)&bufA[r * 64 + (((lq + h * 4) ^ (r & 7)) << 3)]);
      }
#pragma unroll
      for (int j = 0; j < 2; ++j) {
        const int r = wc * 64 + qj * 32 + j * 16 + l15;
#pragma unroll
        for (int h = 0; h < 2; ++h)
          bfr[j][h] = __builtin_bit_cast(
              bf16x8,
              *(const u32x4*)&bufB[r * 64 + (((lq + h * 4) ^ (r & 7)) << 3)]);
      }
      __builtin_amdgcn_s_setprio(1);
#pragma unroll
      for (int i = 0; i < 4; ++i) {
#pragma unroll
        for (int j = 0; j < 2; ++j) {
          acc[qi * 4 + i][qj * 2 + j] =
              mfma16(af[i][0], bfr[j][0], acc[qi * 4 + i][qj * 2 + j]);
          acc[qi * 4 + i][qj * 2 + j] =
              mfma16(af[i][1], bfr[j][1], acc[qi * 4 + i][qj * 2 + j]);
        }
      }
      __builtin_amdgcn_s_setprio(0);
      __builtin_amdgcn_s_barrier();
    }
  }

#pragma unroll
  for (int J = 0; J < 4; ++J) {
    const int colb = n0 + wc * 64 + J * 16 + l15;
    const float bv = bias[colb];
    if constexpr (SPLIT) {
      const int which = colb >> 9;
      const int hh = (colb >> 5) & 15;
      const int d = colb & 31;
      unsigned short* dst = which == 0 ? qo : (which == 1 ? ko : vo);
#pragma unroll
      for (int I = 0; I < 8; ++I) {
#pragma unroll
        for (int r = 0; r < 4; ++r) {
          uint32_t m = (uint32_t)(m0 + wr * 128 + I * 16 + lq * 4 + r);
          uint32_t bw_ = m / 49u;
          uint32_t nn = m - bw_ * 49u;
          dst[((size_t)(bw_ * 16u + hh) * 49u + nn) * 32u + d] =
              f2bf(acc[I][J][r] + bv);
        }
      }
    } else {
#pragma unroll
      for (int I = 0; I < 8; ++I) {
#pragma unroll
        for (int r = 0; r < 4; ++r) {
          size_t m = m0 + wr * 128 + I * 16 + lq * 4 + r;
          fo[m * CDIM + colb] = acc[I][J][r] + bv;
        }
      }
    }
  }
}

// ---- K2: window attention, one wave per (b,h) ----
// P/Vt use stride-64 rows with 16B-slot XOR swizzle (conflict-free reads,
// 48KB/block -> 3 blocks/CU).
__global__ __launch_bounds__(256) void k_attn(
    const unsigned short* __restrict__ qb, const unsigned short* __restrict__ kb,
    const unsigned short* __restrict__ vb, const float* __restrict__ mask,
    unsigned short* __restrict__ ao) {
  __shared__ __attribute__((aligned(16))) unsigned short sP[4][64 * 64];
  __shared__ __attribute__((aligned(16))) unsigned short sV[4][32 * 64];
  const int t = threadIdx.x;
  const int l = t & 63, w = t >> 6;
  const int l15 = l & 15, lq = l >> 4;
  const int pair = blockIdx.x * 4 + w;
  const int b = pair >> 4, h = pair & 15;
  const size_t base = (size_t)pair * (TOK * HDIM);
  unsigned short* P = sP[w];
  unsigned short* Vt = sV[w];

  bf16x8 qf[4], kf[4];
#pragma unroll
  for (int i = 0; i < 4; i++)
    qf[i] = __builtin_bit_cast(
        bf16x8, *(const u32x4*)(qb + base + (size_t)(i * 16 + l15) * 32 + lq * 8));
#pragma unroll
  for (int i = 0; i < 4; i++)
    kf[i] = __builtin_bit_cast(
        bf16x8, *(const u32x4*)(kb + base + (size_t)(i * 16 + l15) * 32 + lq * 8));
  u32x4 vr[4];
#pragma unroll
  for (int j = 0; j < 4; j++)
    vr[j] = *(const u32x4*)(vb + base + (size_t)l * 32 + j * 8);

  // S = Q K^T (64x64 padded; valid 49x49)
  f32x4 s[4][4];
  __builtin_amdgcn_s_setprio(1);
#pragma unroll
  for (int i = 0; i < 4; i++) {
#pragma unroll
    for (int j = 0; j < 4; j++) s[i][j] = mfma16(qf[i], kf[j], (f32x4)0.0f);
  }
  __builtin_amdgcn_s_setprio(0);

  // V^T -> LDS [d=32][token=64] swizzled, zero-padded tokens >= 49
  const bool vok = (l < TOK);
  const int tsl = ((l >> 3) & 7);
  const int tlo = l & 7;
#pragma unroll
  for (int j = 0; j < 4; j++) {
#pragma unroll
    for (int c = 0; c < 4; c++) {
      uint32_t u = vr[j][c];
      int d0 = j * 8 + c * 2;
      Vt[(d0 + 0) * 64 + ((tsl ^ ((d0 + 0) & 7)) << 3) + tlo] =
          vok ? (unsigned short)(u & 0xFFFFu) : (unsigned short)0;
      Vt[(d0 + 1) * 64 + ((tsl ^ ((d0 + 1) & 7)) << 3) + tlo] =
          vok ? (unsigned short)(u >> 16) : (unsigned short)0;
    }
  }

  // scale + window mask
  const float* mrow = mask + (size_t)(b & 63) * (TOK * TOK);
#pragma unroll
  for (int i = 0; i < 4; i++) {
#pragma unroll
    for (int r = 0; r < 4; r++) {
      int row = i * 16 + lq * 4 + r;
#pragma unroll
      for (int j = 0; j < 4; j++) {
        int col = j * 16 + l15;
        float xv = s[i][j][r] * ATT_SCALE;
        if (col < TOK) {
          if (row < TOK) xv += mrow[row * TOK + col];
        } else {
          xv = -1e30f;
        }
        s[i][j][r] = xv;
      }
    }
  }

  // row softmax; unnormalized P -> LDS bf16 (swizzled)
  float rinv[4][4];
#pragma unroll
  for (int i = 0; i < 4; i++) {
#pragma unroll
    for (int r = 0; r < 4; r++) {
      float m = fmaxf(fmaxf(s[i][0][r], s[i][1][r]), fmaxf(s[i][2][r], s[i][3][r]));
      m = fmaxf(m, __shfl_xor(m, 1));
      m = fmaxf(m, __shfl_xor(m, 2));
      m = fmaxf(m, __shfl_xor(m, 4));
      m = fmaxf(m, __shfl_xor(m, 8));
      float sum = 0.f;
      int row = i * 16 + lq * 4 + r;
#pragma unroll
      for (int j = 0; j < 4; j++) {
        float p = __expf(s[i][j][r] - m);
        sum += p;
        P[row * 64 + (((j * 2 + (l15 >> 3)) ^ (row & 7)) << 3) + (l15 & 7)] =
            f2bf(p);
      }
      sum += __shfl_xor(sum, 1);
      sum += __shfl_xor(sum, 2);
      sum += __shfl_xor(sum, 4);
      sum += __shfl_xor(sum, 8);
      rinv[i][r] = 1.0f / sum;
    }
  }

  asm volatile("s_waitcnt lgkmcnt(0)" ::: "memory");
  __builtin_amdgcn_sched_barrier(0);

  // O = P @ V (K = 64 padded tokens, N = 32 dims)
  f32x4 o[4][2] = {};
#pragma unroll
  for (int ks = 0; ks < 2; ks++) {
    bf16x8 pa[4], vf[2];
#pragma unroll
    for (int i = 0; i < 4; i++)
      pa[i] = __builtin_bit_cast(
          bf16x8,
          *(const u32x4*)&P[(i * 16 + l15) * 64 + (((lq + ks * 4) ^ (l15 & 7)) << 3)]);
#pragma unroll
    for (int j = 0; j < 2; j++)
      vf[j] = __builtin_bit_cast(
          bf16x8,
          *(const u32x4*)&Vt[(j * 16 + l15) * 64 + (((lq + ks * 4) ^ (l15 & 7)) << 3)]);
    __builtin_amdgcn_s_setprio(1);
#pragma unroll
    for (int i = 0; i < 4; i++) {
#pragma unroll
      for (int j = 0; j < 2; j++) o[i][j] = mfma16(pa[i], vf[j], o[i][j]);
    }
    __builtin_amdgcn_s_setprio(0);
  }

#pragma unroll
  for (int i = 0; i < 4; i++) {
#pragma unroll
    for (int r = 0; r < 4; r++) {
      int row = i * 16 + lq * 4 + r;
      if (row < TOK) {
        float inv = rinv[i][r];
        size_t obase = ((size_t)b * TOK + row) * CDIM + h * HDIM;
#pragma unroll
        for (int j = 0; j < 2; j++)
          ao[obase + j * 16 + l15] = f2bf(o[i][j][r] * inv);
      }
    }
  }
}

extern "C" void kernel_launch(void* const* d_in, const int* in_sizes, int n_in,
                              void* d_out, int out_size, void* d_ws,
                              size_t ws_size, hipStream_t stream) {
  const float* x = (const float*)d_in[0];
  const float* mask = (const float*)d_in[1];
  const float* Wqkv = (const float*)d_in[2];
  const float* bqkv = (const float*)d_in[3];
  const float* Adown = (const float*)d_in[4];
  const float* Bup = (const float*)d_in[5];
  const float* Wproj = (const float*)d_in[6];
  const float* bproj = (const float*)d_in[7];
  float* out = (float*)d_out;
  char* ws = (char*)d_ws;

  size_t off = 0;
  auto alloc = [&](size_t bytes) {
    size_t o = off;
    off += (bytes + 255) & ~(size_t)255;
    return o;
  };
  const size_t qkv_elems = (size_t)NB * NHEAD * TOK * HDIM;
  unsigned short* weff = (unsigned short*)(ws + alloc((size_t)3 * CDIM * CDIM * 2));
  unsigned short* wpb = (unsigned short*)(ws + alloc((size_t)CDIM * CDIM * 2));
  unsigned short* qb = (unsigned short*)(ws + alloc(qkv_elems * 2 + 4096));
  unsigned short* kb = (unsigned short*)(ws + alloc(qkv_elems * 2 + 4096));
  unsigned short* vb = (unsigned short*)(ws + alloc(qkv_elems * 2 + 4096));
  unsigned short* xb = (unsigned short*)(ws + alloc((size_t)MTOT * CDIM * 2));
  unsigned short* ao = xb;  // xb dead after QKV GEMM; reuse for attention out

  k_prep_weff<<<(3 * CDIM * CDIM + 255) / 256, 256, 0, stream>>>(Wqkv, Bup,
                                                                 Adown, weff);
  k_conv4<<<256, 256, 0, stream>>>(Wproj, wpb, CDIM * CDIM / 4);
  k_conv4<<<2048, 256, 0, stream>>>(x, xb, MTOT * CDIM / 4);
  // QKV: 392 m-tiles x 6 n-tiles = 2352 blocks (2352 % 8 == 0)
  k_gemm256<6, true><<<(MTOT / 256) * 6, 512, 0, stream>>>(
      xb, weff, bqkv, qb, kb, vb, nullptr);
  k_attn<<<NB * NHEAD / 4, 256, 0, stream>>>(qb, kb, vb, mask, ao);
  // proj: 392 x 2 = 784 blocks (784 % 8 == 0)
  k_gemm256<2, false><<<(MTOT / 256) * 2, 512, 0, stream>>>(
      ao, wpb, bproj, nullptr, nullptr, nullptr, out);
}

// Round 3
// 606.299 us; speedup vs baseline: 1.1082x; 1.0350x over previous
//
#include <hip/hip_runtime.h>
#include <stdint.h>

typedef __attribute__((ext_vector_type(4))) float f32x4;
typedef __attribute__((ext_vector_type(8))) __bf16 bf16x8;
typedef __attribute__((ext_vector_type(4))) unsigned int u32x4;
typedef __attribute__((ext_vector_type(4))) unsigned short u16x4;

#define TOK 49
#define NHEAD 16
#define HDIM 32
#define CDIM 512
#define NB 2048
#define MTOT (NB * TOK) /* 100352 */
#define ATT_SCALE 0.17677669529663687f

__device__ __forceinline__ unsigned short f2bf(float f) {
  uint32_t u = __builtin_bit_cast(uint32_t, f);
  u += 0x7FFFu + ((u >> 16) & 1u);
  return (unsigned short)(u >> 16);
}

__device__ __forceinline__ void gl_lds16(const void* g, const void* lds) {
  __builtin_amdgcn_global_load_lds(
      (__attribute__((address_space(1))) void*)(uintptr_t)g,
      (__attribute__((address_space(3))) void*)(uint32_t)(uintptr_t)lds,
      16, 0, 0);
}

__device__ __forceinline__ f32x4 mfma16(bf16x8 a, bf16x8 b, f32x4 c) {
  return __builtin_amdgcn_mfma_f32_16x16x32_bf16(a, b, c, 0, 0, 0);
}

// ---- K0a: W_eff = W_qkv + B_up @ A_down, to bf16 [1536][512] ----
__global__ __launch_bounds__(256) void k_prep_weff(
    const float* __restrict__ Wqkv, const float* __restrict__ Bup,
    const float* __restrict__ Adown, unsigned short* __restrict__ weff) {
  int idx = blockIdx.x * 256 + threadIdx.x;
  if (idx >= 3 * CDIM * CDIM) return;
  int o = idx >> 9, i = idx & 511;
  float v = Wqkv[idx];
#pragma unroll
  for (int r = 0; r < 4; r++) v += Bup[o * 4 + r] * Adown[r * 512 + i];
  weff[idx] = f2bf(v);
}

// ---- K0b: fp32 -> bf16 vectorized convert ----
__global__ __launch_bounds__(256) void k_conv4(
    const float* __restrict__ src, unsigned short* __restrict__ dst, int n4) {
  for (int i = blockIdx.x * blockDim.x + threadIdx.x; i < n4;
       i += gridDim.x * blockDim.x) {
    f32x4 v = *(const f32x4*)(src + (size_t)i * 4);
    u16x4 o;
    o[0] = f2bf(v[0]); o[1] = f2bf(v[1]); o[2] = f2bf(v[2]); o[3] = f2bf(v[3]);
    *(u16x4*)(dst + (size_t)i * 4) = o;
  }
}

// ---- 256x256 tile, BK=64, 8-wave, counted-vmcnt pipelined GEMM ----
// C = A @ Bw^T + bias. A [M][512] bf16, Bw [N][512] bf16 (B^T form).
// LDS 16B slots XOR-swizzled via pre-swizzled global source (LDS dest linear).
// Inner loop: zero-redundancy fragment loads — B frags loaded once per K-tile
// (8 reads), A frags once (16 reads) via 2-deep register rotation so phase
// p+1 ds_reads overlap phase p MFMAs. 24 KB LDS reads /wave /K-tile (floor).
template <int NT, bool SPLIT>
__global__ __launch_bounds__(512, 1) void k_gemm256(
    const unsigned short* __restrict__ A, const unsigned short* __restrict__ Bw,
    const float* __restrict__ bias,
    unsigned short* __restrict__ qo, unsigned short* __restrict__ ko,
    unsigned short* __restrict__ vo, float* __restrict__ fo) {
  __shared__ __attribute__((aligned(16))) unsigned short lA[2][256 * 64];
  __shared__ __attribute__((aligned(16))) unsigned short lB[2][256 * 64];
  const int t = threadIdx.x;
  const int l = t & 63;
  const int l15 = l & 15, lq = l >> 4;
  const int w = t >> 6;
  const int wr = w >> 2, wc = w & 3;  // 2 x 4 wave grid, wave owns 128x64
  const int bid = blockIdx.x;
  const int lb = (bid & 7) * ((int)gridDim.x >> 3) + (bid >> 3);
  const int mt = lb / NT, nt = lb % NT;
  const size_t m0 = (size_t)mt * 256;
  const int n0 = nt * 256;

  auto stage = [&](int kt, int bb) {
#pragma unroll
    for (int q = 0; q < 4; ++q) {
      const int li = q * 512 + t;  // linear 16B-chunk index in 256x64 tile
      const int row = li >> 3, sl = li & 7;
      gl_lds16(A + (m0 + row) * CDIM + kt * 64 + ((sl ^ (row & 7)) << 3),
               &lA[bb][li * 8]);
    }
#pragma unroll
    for (int q = 0; q < 4; ++q) {
      const int li = q * 512 + t;
      const int row = li >> 3, sl = li & 7;
      gl_lds16(Bw + (size_t)(n0 + row) * CDIM + kt * 64 + ((sl ^ (row & 7)) << 3),
               &lB[bb][li * 8]);
    }
  };

  f32x4 acc[8][4] = {};
  stage(0, 0);
  for (int kt = 0; kt < 8; ++kt) {
    const int cur = kt & 1;
    if (kt < 7) {
      stage(kt + 1, cur ^ 1);
      // tile kt's 8 loads landed; tile kt+1's 8 stay in flight (counted)
      asm volatile("s_waitcnt vmcnt(8)" ::: "memory");
    } else {
      asm volatile("s_waitcnt vmcnt(0)" ::: "memory");
    }
    __builtin_amdgcn_s_barrier();
    asm volatile("" ::: "memory");  // keep ds_reads below the barrier
    const unsigned short* bufA = &lA[cur][0];
    const unsigned short* bufB = &lB[cur][0];

    // B fragments: loaded ONCE per K-tile, live across all 4 phases
    bf16x8 bfr[4][2];
#pragma unroll
    for (int c = 0; c < 4; ++c) {
      const int r = wc * 64 + c * 16 + l15;
#pragma unroll
      for (int h = 0; h < 2; ++h)
        bfr[c][h] = __builtin_bit_cast(
            bf16x8,
            *(const u32x4*)&bufB[r * 64 + (((lq + h * 4) ^ (r & 7)) << 3)]);
    }

    auto loadA = [&](bf16x8(&dst)[2][2], int p) {
#pragma unroll
      for (int rr = 0; rr < 2; ++rr) {
        const int r = wr * 128 + (p * 2 + rr) * 16 + l15;
#pragma unroll
        for (int h = 0; h < 2; ++h)
          dst[rr][h] = __builtin_bit_cast(
              bf16x8,
              *(const u32x4*)&bufA[r * 64 + (((lq + h * 4) ^ (r & 7)) << 3)]);
      }
    };

    bf16x8 afA[2][2], afB[2][2];
    loadA(afA, 0);
#pragma unroll
    for (int p = 0; p < 4; ++p) {
      bf16x8(&cur_)[2][2] = (p & 1) ? afB : afA;
      bf16x8(&nxt_)[2][2] = (p & 1) ? afA : afB;
      if (p < 3) loadA(nxt_, p + 1);  // next phase reads overlap this MFMA
      __builtin_amdgcn_s_setprio(1);
#pragma unroll
      for (int rr = 0; rr < 2; ++rr) {
#pragma unroll
        for (int c = 0; c < 4; ++c) {
          acc[p * 2 + rr][c] = mfma16(cur_[rr][0], bfr[c][0], acc[p * 2 + rr][c]);
          acc[p * 2 + rr][c] = mfma16(cur_[rr][1], bfr[c][1], acc[p * 2 + rr][c]);
        }
      }
      __builtin_amdgcn_s_setprio(0);
    }
    asm volatile("" ::: "memory");
    __builtin_amdgcn_s_barrier();  // all reads of buf[cur] done -> safe to
                                   // overwrite next iter
  }

#pragma unroll
  for (int J = 0; J < 4; ++J) {
    const int colb = n0 + wc * 64 + J * 16 + l15;
    const float bv = bias[colb];
    if constexpr (SPLIT) {
      const int which = colb >> 9;
      const int hh = (colb >> 5) & 15;
      const int d = colb & 31;
      unsigned short* dst = which == 0 ? qo : (which == 1 ? ko : vo);
#pragma unroll
      for (int I = 0; I < 8; ++I) {
#pragma unroll
        for (int r = 0; r < 4; ++r) {
          uint32_t m = (uint32_t)(m0 + wr * 128 + I * 16 + lq * 4 + r);
          uint32_t bw_ = m / 49u;
          uint32_t nn = m - bw_ * 49u;
          dst[((size_t)(bw_ * 16u + hh) * 49u + nn) * 32u + d] =
              f2bf(acc[I][J][r] + bv);
        }
      }
    } else {
#pragma unroll
      for (int I = 0; I < 8; ++I) {
#pragma unroll
        for (int r = 0; r < 4; ++r) {
          size_t m = m0 + wr * 128 + I * 16 + lq * 4 + r;
          fo[m * CDIM + colb] = acc[I][J][r] + bv;
        }
      }
    }
  }
}

// ---- K2: window attention, one wave per (b,h) ---- (unchanged this round)
__global__ __launch_bounds__(256) void k_attn(
    const unsigned short* __restrict__ qb, const unsigned short* __restrict__ kb,
    const unsigned short* __restrict__ vb, const float* __restrict__ mask,
    unsigned short* __restrict__ ao) {
  __shared__ __attribute__((aligned(16))) unsigned short sP[4][64 * 64];
  __shared__ __attribute__((aligned(16))) unsigned short sV[4][32 * 64];
  const int t = threadIdx.x;
  const int l = t & 63, w = t >> 6;
  const int l15 = l & 15, lq = l >> 4;
  const int pair = blockIdx.x * 4 + w;
  const int b = pair >> 4, h = pair & 15;
  const size_t base = (size_t)pair * (TOK * HDIM);
  unsigned short* P = sP[w];
  unsigned short* Vt = sV[w];

  bf16x8 qf[4], kf[4];
#pragma unroll
  for (int i = 0; i < 4; i++)
    qf[i] = __builtin_bit_cast(
        bf16x8, *(const u32x4*)(qb + base + (size_t)(i * 16 + l15) * 32 + lq * 8));
#pragma unroll
  for (int i = 0; i < 4; i++)
    kf[i] = __builtin_bit_cast(
        bf16x8, *(const u32x4*)(kb + base + (size_t)(i * 16 + l15) * 32 + lq * 8));
  u32x4 vr[4];
#pragma unroll
  for (int j = 0; j < 4; j++)
    vr[j] = *(const u32x4*)(vb + base + (size_t)l * 32 + j * 8);

  // S = Q K^T (64x64 padded; valid 49x49)
  f32x4 s[4][4];
  __builtin_amdgcn_s_setprio(1);
#pragma unroll
  for (int i = 0; i < 4; i++) {
#pragma unroll
    for (int j = 0; j < 4; j++) s[i][j] = mfma16(qf[i], kf[j], (f32x4)0.0f);
  }
  __builtin_amdgcn_s_setprio(0);

  // V^T -> LDS [d=32][token=64] swizzled, zero-padded tokens >= 49
  const bool vok = (l < TOK);
  const int tsl = ((l >> 3) & 7);
  const int tlo = l & 7;
#pragma unroll
  for (int j = 0; j < 4; j++) {
#pragma unroll
    for (int c = 0; c < 4; c++) {
      uint32_t u = vr[j][c];
      int d0 = j * 8 + c * 2;
      Vt[(d0 + 0) * 64 + ((tsl ^ ((d0 + 0) & 7)) << 3) + tlo] =
          vok ? (unsigned short)(u & 0xFFFFu) : (unsigned short)0;
      Vt[(d0 + 1) * 64 + ((tsl ^ ((d0 + 1) & 7)) << 3) + tlo] =
          vok ? (unsigned short)(u >> 16) : (unsigned short)0;
    }
  }

  // scale + window mask
  const float* mrow = mask + (size_t)(b & 63) * (TOK * TOK);
#pragma unroll
  for (int i = 0; i < 4; i++) {
#pragma unroll
    for (int r = 0; r < 4; r++) {
      int row = i * 16 + lq * 4 + r;
#pragma unroll
      for (int j = 0; j < 4; j++) {
        int col = j * 16 + l15;
        float xv = s[i][j][r] * ATT_SCALE;
        if (col < TOK) {
          if (row < TOK) xv += mrow[row * TOK + col];
        } else {
          xv = -1e30f;
        }
        s[i][j][r] = xv;
      }
    }
  }

  // row softmax; unnormalized P -> LDS bf16 (swizzled)
  float rinv[4][4];
#pragma unroll
  for (int i = 0; i < 4; i++) {
#pragma unroll
    for (int r = 0; r < 4; r++) {
      float m = fmaxf(fmaxf(s[i][0][r], s[i][1][r]), fmaxf(s[i][2][r], s[i][3][r]));
      m = fmaxf(m, __shfl_xor(m, 1));
      m = fmaxf(m, __shfl_xor(m, 2));
      m = fmaxf(m, __shfl_xor(m, 4));
      m = fmaxf(m, __shfl_xor(m, 8));
      float sum = 0.f;
      int row = i * 16 + lq * 4 + r;
#pragma unroll
      for (int j = 0; j < 4; j++) {
        float p = __expf(s[i][j][r] - m);
        sum += p;
        P[row * 64 + (((j * 2 + (l15 >> 3)) ^ (row & 7)) << 3) + (l15 & 7)] =
            f2bf(p);
      }
      sum += __shfl_xor(sum, 1);
      sum += __shfl_xor(sum, 2);
      sum += __shfl_xor(sum, 4);
      sum += __shfl_xor(sum, 8);
      rinv[i][r] = 1.0f / sum;
    }
  }

  asm volatile("s_waitcnt lgkmcnt(0)" ::: "memory");
  __builtin_amdgcn_sched_barrier(0);

  // O = P @ V (K = 64 padded tokens, N = 32 dims)
  f32x4 o[4][2] = {};
#pragma unroll
  for (int ks = 0; ks < 2; ks++) {
    bf16x8 pa[4], vf[2];
#pragma unroll
    for (int i = 0; i < 4; i++)
      pa[i] = __builtin_bit_cast(
          bf16x8,
          *(const u32x4*)&P[(i * 16 + l15) * 64 + (((lq + ks * 4) ^ (l15 & 7)) << 3)]);
#pragma unroll
    for (int j = 0; j < 2; j++)
      vf[j] = __builtin_bit_cast(
          bf16x8,
          *(const u32x4*)&Vt[(j * 16 + l15) * 64 + (((lq + ks * 4) ^ (l15 & 7)) << 3)]);
    __builtin_amdgcn_s_setprio(1);
#pragma unroll
    for (int i = 0; i < 4; i++) {
#pragma unroll
      for (int j = 0; j < 2; j++) o[i][j] = mfma16(pa[i], vf[j], o[i][j]);
    }
    __builtin_amdgcn_s_setprio(0);
  }

#pragma unroll
  for (int i = 0; i < 4; i++) {
#pragma unroll
    for (int r = 0; r < 4; r++) {
      int row = i * 16 + lq * 4 + r;
      if (row < TOK) {
        float inv = rinv[i][r];
        size_t obase = ((size_t)b * TOK + row) * CDIM + h * HDIM;
#pragma unroll
        for (int j = 0; j < 2; j++)
          ao[obase + j * 16 + l15] = f2bf(o[i][j][r] * inv);
      }
    }
  }
}

extern "C" void kernel_launch(void* const* d_in, const int* in_sizes, int n_in,
                              void* d_out, int out_size, void* d_ws,
                              size_t ws_size, hipStream_t stream) {
  const float* x = (const float*)d_in[0];
  const float* mask = (const float*)d_in[1];
  const float* Wqkv = (const float*)d_in[2];
  const float* bqkv = (const float*)d_in[3];
  const float* Adown = (const float*)d_in[4];
  const float* Bup = (const float*)d_in[5];
  const float* Wproj = (const float*)d_in[6];
  const float* bproj = (const float*)d_in[7];
  float* out = (float*)d_out;
  char* ws = (char*)d_ws;

  size_t off = 0;
  auto alloc = [&](size_t bytes) {
    size_t o = off;
    off += (bytes + 255) & ~(size_t)255;
    return o;
  };
  const size_t qkv_elems = (size_t)NB * NHEAD * TOK * HDIM;
  unsigned short* weff = (unsigned short*)(ws + alloc((size_t)3 * CDIM * CDIM * 2));
  unsigned short* wpb = (unsigned short*)(ws + alloc((size_t)CDIM * CDIM * 2));
  unsigned short* qb = (unsigned short*)(ws + alloc(qkv_elems * 2 + 4096));
  unsigned short* kb = (unsigned short*)(ws + alloc(qkv_elems * 2 + 4096));
  unsigned short* vb = (unsigned short*)(ws + alloc(qkv_elems * 2 + 4096));
  unsigned short* xb = (unsigned short*)(ws + alloc((size_t)MTOT * CDIM * 2));
  unsigned short* ao = xb;  // xb dead after QKV GEMM; reuse for attention out

  k_prep_weff<<<(3 * CDIM * CDIM + 255) / 256, 256, 0, stream>>>(Wqkv, Bup,
                                                                 Adown, weff);
  k_conv4<<<256, 256, 0, stream>>>(Wproj, wpb, CDIM * CDIM / 4);
  k_conv4<<<2048, 256, 0, stream>>>(x, xb, MTOT * CDIM / 4);
  // QKV: 392 m-tiles x 6 n-tiles = 2352 blocks (2352 % 8 == 0)
  k_gemm256<6, true><<<(MTOT / 256) * 6, 512, 0, stream>>>(
      xb, weff, bqkv, qb, kb, vb, nullptr);
  k_attn<<<NB * NHEAD / 4, 256, 0, stream>>>(qb, kb, vb, mask, ao);
  // proj: 392 x 2 = 784 blocks (784 % 8 == 0)
  k_gemm256<2, false><<<(MTOT / 256) * 2, 512, 0, stream>>>(
      ao, wpb, bproj, nullptr, nullptr, nullptr, out);
}